// Round 2
// baseline (3318.473 us; speedup 1.0000x reference)
//
#include <hip/hip_runtime.h>
#include <math.h>

#define B_    64
#define CIN   64
#define COUT  128
#define HWHW  4096   // 64*64
#define NPIX  (B_ * COUT * HWHW)   // 33,554,432 per output map

// ---------------------------------------------------------------------------
// Fused: P_new = a*P + (1-a)*Q  ->  conv5x5(P_new, W) + bias - gamma*R = U
//        S = (U > 1)            ->  write S, U   (f32 fast path)
// Block: 256 threads = 16 local couts x 16 spatial threads.
// Each spatial thread owns a 4x4 output patch of a 16x16 tile.
// ---------------------------------------------------------------------------
__global__ __launch_bounds__(256) void lif_conv_kernel(
    const float* __restrict__ P, const float* __restrict__ Q,
    const float* __restrict__ R, const float* __restrict__ W,
    const float* __restrict__ bias, float* __restrict__ out,
    float alpha, float oma, float gamma)
{
    const int tid = threadIdx.x;
    const int b   = blockIdx.z;
    const int cog = blockIdx.y;                 // cout group of 16 (0..7)
    const int ty0 = (blockIdx.x >> 2) << 4;     // tile origin y (0,16,32,48)
    const int tx0 = (blockIdx.x & 3) << 4;      // tile origin x
    const int col = tid >> 4;                   // local cout 0..15
    const int sp  = tid & 15;
    const int sy  = (sp >> 2) << 2;             // 0,4,8,12
    const int sx  = (sp & 3) << 2;
    const int co  = (cog << 4) + col;

    __shared__ float in_lds[400];               // 20x20 input tile (row stride 20)
    __shared__ float w_lds[400];                // 16 couts x 25 taps

    float acc[16];
#pragma unroll
    for (int i = 0; i < 16; ++i) acc[i] = 0.f;

    const float* Pb = P + (size_t)b * CIN * HWHW;
    const float* Qb = Q + (size_t)b * CIN * HWHW;
    const float* Wg = W + (size_t)(cog << 4) * CIN * 25;

    for (int cin = 0; cin < CIN; ++cin) {
        __syncthreads();
        // stage 20x20 P_new tile, origin (ty0-2, tx0-2), zero-padded
        for (int idx = tid; idx < 400; idx += 256) {
            int r  = idx / 20;
            int c  = idx - r * 20;
            int gy = ty0 - 2 + r;
            int gx = tx0 - 2 + c;
            float v = 0.f;
            if ((unsigned)gy < 64u && (unsigned)gx < 64u) {
                int off = cin * HWHW + (gy << 6) + gx;
                v = alpha * Pb[off] + oma * Qb[off];
            }
            in_lds[idx] = v;
        }
        // stage weights for this cin: 16 couts x 25
        for (int idx = tid; idx < 400; idx += 256) {
            int cl = idx / 25;
            int k  = idx - cl * 25;
            w_lds[idx] = Wg[(size_t)(cl * CIN + cin) * 25 + k];
        }
        __syncthreads();

        // 8x8 input window into registers (rows sy..sy+7, cols sx..sx+7)
        float win[8][8];
#pragma unroll
        for (int r = 0; r < 8; ++r) {
            float4 a0 = *(const float4*)&in_lds[(sy + r) * 20 + sx];
            float4 a1 = *(const float4*)&in_lds[(sy + r) * 20 + sx + 4];
            win[r][0] = a0.x; win[r][1] = a0.y; win[r][2] = a0.z; win[r][3] = a0.w;
            win[r][4] = a1.x; win[r][5] = a1.y; win[r][6] = a1.z; win[r][7] = a1.w;
        }

        const float* wrow = &w_lds[col * 25];
#pragma unroll
        for (int dy = 0; dy < 5; ++dy) {
#pragma unroll
            for (int dx = 0; dx < 5; ++dx) {
                float w = wrow[dy * 5 + dx];
#pragma unroll
                for (int p = 0; p < 4; ++p)
#pragma unroll
                    for (int q = 0; q < 4; ++q)
                        acc[(p << 2) + q] = fmaf(w, win[p + dy][q + dx], acc[(p << 2) + q]);
            }
        }
    }

    // epilogue: U = acc + bias - gamma*R ; S = (U > 1)
    const float bv = bias[co];
    const size_t plane = ((size_t)b * COUT + co) * HWHW;
    const float* Rp = R + plane;
    float* Sp = out + plane;
    float* Up = out + (size_t)NPIX + plane;
#pragma unroll
    for (int p = 0; p < 4; ++p) {
        int oy = ty0 + sy + p;
        int ro = (oy << 6) + tx0 + sx;
        float4 r4 = *(const float4*)&Rp[ro];
        float u0 = acc[(p << 2) + 0] + bv - gamma * r4.x;
        float u1 = acc[(p << 2) + 1] + bv - gamma * r4.y;
        float u2 = acc[(p << 2) + 2] + bv - gamma * r4.z;
        float u3 = acc[(p << 2) + 3] + bv - gamma * r4.w;
        float4 uq = make_float4(u0, u1, u2, u3);
        float4 sq = make_float4(u0 > 1.f ? 1.f : 0.f,
                                u1 > 1.f ? 1.f : 0.f,
                                u2 > 1.f ? 1.f : 0.f,
                                u3 > 1.f ? 1.f : 0.f);
        *(float4*)&Sp[ro] = sq;
        *(float4*)&Up[ro] = uq;
    }
}

// ---------------------------------------------------------------------------
// f64 repair: spike decisions with |U_f32 - 1| < TAU are re-derived in full
// f64 (P_new, products, bias, R all double). f32 reorder error is <~1e-5,
// TAU = 5e-4 gives ~50x margin; ~8k of 33.5M elements take the slow path.
// ---------------------------------------------------------------------------
#define TAU 5e-4f

__global__ __launch_bounds__(256) void repair_kernel(
    const float* __restrict__ P, const float* __restrict__ Q,
    const float* __restrict__ R, const float* __restrict__ W,
    const float* __restrict__ bias, float* __restrict__ out,
    double alpha, double oma, double gamma)
{
    const int stride = gridDim.x * 256;
    for (int idx = blockIdx.x * 256 + threadIdx.x; idx < NPIX; idx += stride) {
        float u = out[(size_t)NPIX + idx];
        if (fabsf(u - 1.0f) >= TAU) continue;

        const int plane = idx >> 12;         // b*COUT + co
        const int pix   = idx & 4095;
        const int oy    = pix >> 6;
        const int ox    = pix & 63;
        const int b     = plane >> 7;
        const int co    = plane & 127;

        const float* Pb = P + (size_t)b * CIN * HWHW;
        const float* Qb = Q + (size_t)b * CIN * HWHW;
        const float* Wc = W + (size_t)co * CIN * 25;

        double acc = 0.0;
        for (int cin = 0; cin < CIN; ++cin) {
            for (int dy = 0; dy < 5; ++dy) {
                int iy = oy + dy - 2;
                if ((unsigned)iy >= 64u) continue;
                for (int dx = 0; dx < 5; ++dx) {
                    int ix = ox + dx - 2;
                    if ((unsigned)ix >= 64u) continue;
                    int off = cin * HWHW + (iy << 6) + ix;
                    double pn = alpha * (double)Pb[off] + oma * (double)Qb[off];
                    acc = fma((double)Wc[cin * 25 + dy * 5 + dx], pn, acc);
                }
            }
        }
        double u64 = acc + (double)bias[co]
                   - gamma * (double)R[(size_t)plane * HWHW + pix];
        out[idx]                 = (u64 > 1.0) ? 1.f : 0.f;
        out[(size_t)NPIX + idx]  = (float)u64;
    }
}

// readout init: ro[i] = 0.5 (the "+1)*0.5" constant term)
__global__ void ro_init(float* ro)
{
    int i = blockIdx.x * 256 + threadIdx.x;
    if (i < 640) ro[i] = 0.5f;
}

// ---------------------------------------------------------------------------
// readout[b][o] += 0.5 * sum_f maxpool(S)[b][f] * w_sign[o][f]
// Block = one (b, channel). Pool recomputed from S (in d_out) on the fly.
// ---------------------------------------------------------------------------
__global__ __launch_bounds__(256) void readout_kernel(
    const float* __restrict__ S, const float* __restrict__ wsig,
    float* __restrict__ ro)
{
    const int tid = threadIdx.x;
    const int b = blockIdx.x >> 7;
    const int c = blockIdx.x & 127;

    __shared__ float wl[10 * 1024];
    for (int idx = tid; idx < 10240; idx += 256) {
        int o = idx >> 10;
        int f = idx & 1023;
        wl[idx] = wsig[(size_t)o * 131072 + (c << 10) + f];
    }
    __syncthreads();

    float acc[10];
#pragma unroll
    for (int o = 0; o < 10; ++o) acc[o] = 0.f;

    const float* Sp = S + ((size_t)b * COUT + c) * HWHW;
#pragma unroll
    for (int i = 0; i < 4; ++i) {
        int fl = tid + (i << 8);               // 0..1023
        int ph = fl >> 5, pw = fl & 31;
        const float2 t0 = *(const float2*)&Sp[(ph << 7) + (pw << 1)];
        const float2 t1 = *(const float2*)&Sp[(ph << 7) + 64 + (pw << 1)];
        float m = fmaxf(fmaxf(t0.x, t0.y), fmaxf(t1.x, t1.y));
#pragma unroll
        for (int o = 0; o < 10; ++o)
            acc[o] = fmaf(m, wl[(o << 10) + fl], acc[o]);
    }

    __shared__ float part[4][10];
    const int wave = tid >> 6;
    const int lane = tid & 63;
#pragma unroll
    for (int o = 0; o < 10; ++o) {
        float v = acc[o];
        v += __shfl_down(v, 32, 64);
        v += __shfl_down(v, 16, 64);
        v += __shfl_down(v, 8, 64);
        v += __shfl_down(v, 4, 64);
        v += __shfl_down(v, 2, 64);
        v += __shfl_down(v, 1, 64);
        if (lane == 0) part[wave][o] = v;
    }
    __syncthreads();
    if (tid < 10) {
        float s = part[0][tid] + part[1][tid] + part[2][tid] + part[3][tid];
        atomicAdd(&ro[b * 10 + tid], 0.5f * s);
    }
}

extern "C" void kernel_launch(void* const* d_in, const int* in_sizes, int n_in,
                              void* d_out, int out_size, void* d_ws, size_t ws_size,
                              hipStream_t stream)
{
    // inputs: 0=input_t (UNUSED: Q_new is dead code), 1=P, 2=Q, 3=R,
    //         4=weights, 5=bias, 6=w_sign
    const float* P    = (const float*)d_in[1];
    const float* Q    = (const float*)d_in[2];
    const float* R    = (const float*)d_in[3];
    const float* W    = (const float*)d_in[4];
    const float* bias = (const float*)d_in[5];
    const float* wsig = (const float*)d_in[6];
    float* out = (float*)d_out;

    const double alpha_d = exp(-1e-3 / 20e-3);
    const double oma_d   = 1.0 - alpha_d;
    const double gamma_d = exp(-1e-3 / 2.86e-3);

    dim3 grid(16, 8, 64);  // 16 spatial tiles x 8 cout groups x 64 batches
    lif_conv_kernel<<<grid, 256, 0, stream>>>(P, Q, R, W, bias, out,
                                              (float)alpha_d, (float)oma_d,
                                              (float)gamma_d);

    repair_kernel<<<8192, 256, 0, stream>>>(P, Q, R, W, bias, out,
                                            alpha_d, oma_d, gamma_d);

    float* ro = out + (size_t)2 * NPIX;
    ro_init<<<3, 256, 0, stream>>>(ro);
    readout_kernel<<<8192, 256, 0, stream>>>(out, wsig, ro);
}

// Round 3
// 1991.733 us; speedup vs baseline: 1.6661x; 1.6661x over previous
//
#include <hip/hip_runtime.h>
#include <math.h>

#define B_    64
#define CIN   64
#define COUT  128
#define HWHW  4096   // 64*64
#define NPIX  (B_ * COUT * HWHW)   // 33,554,432 per output map
#define TAU   5e-4f

// ---------------------------------------------------------------------------
// Fused: P_new = a*P + (1-a)*Q  ->  conv5x5(P_new, W) + bias - gamma*R = U
//        S = (U > 1)            ->  write S, U   (f32 fast path)
// Epilogue also appends indices with |U-1| < TAU to a repair list in d_ws.
// Block: 256 threads = 16 local couts x 16 spatial threads.
// ---------------------------------------------------------------------------
__global__ __launch_bounds__(256) void lif_conv_kernel(
    const float* __restrict__ P, const float* __restrict__ Q,
    const float* __restrict__ R, const float* __restrict__ W,
    const float* __restrict__ bias, float* __restrict__ out,
    unsigned* __restrict__ cnt, int* __restrict__ list, int cap,
    float alpha, float oma, float gamma)
{
    const int tid = threadIdx.x;
    const int b   = blockIdx.z;
    const int cog = blockIdx.y;                 // cout group of 16 (0..7)
    const int ty0 = (blockIdx.x >> 2) << 4;     // tile origin y (0,16,32,48)
    const int tx0 = (blockIdx.x & 3) << 4;      // tile origin x
    const int col = tid >> 4;                   // local cout 0..15
    const int sp  = tid & 15;
    const int sy  = (sp >> 2) << 2;             // 0,4,8,12
    const int sx  = (sp & 3) << 2;
    const int co  = (cog << 4) + col;

    __shared__ float in_lds[400];               // 20x20 input tile (row stride 20)
    __shared__ float w_lds[400];                // 16 couts x 25 taps

    float acc[16];
#pragma unroll
    for (int i = 0; i < 16; ++i) acc[i] = 0.f;

    const float* Pb = P + (size_t)b * CIN * HWHW;
    const float* Qb = Q + (size_t)b * CIN * HWHW;
    const float* Wg = W + (size_t)(cog << 4) * CIN * 25;

    for (int cin = 0; cin < CIN; ++cin) {
        __syncthreads();
        // stage 20x20 P_new tile, origin (ty0-2, tx0-2), zero-padded
        for (int idx = tid; idx < 400; idx += 256) {
            int r  = idx / 20;
            int c  = idx - r * 20;
            int gy = ty0 - 2 + r;
            int gx = tx0 - 2 + c;
            float v = 0.f;
            if ((unsigned)gy < 64u && (unsigned)gx < 64u) {
                int off = cin * HWHW + (gy << 6) + gx;
                v = alpha * Pb[off] + oma * Qb[off];
            }
            in_lds[idx] = v;
        }
        // stage weights for this cin: 16 couts x 25
        for (int idx = tid; idx < 400; idx += 256) {
            int cl = idx / 25;
            int k  = idx - cl * 25;
            w_lds[idx] = Wg[(size_t)(cl * CIN + cin) * 25 + k];
        }
        __syncthreads();

        // 8x8 input window into registers
        float win[8][8];
#pragma unroll
        for (int r = 0; r < 8; ++r) {
            float4 a0 = *(const float4*)&in_lds[(sy + r) * 20 + sx];
            float4 a1 = *(const float4*)&in_lds[(sy + r) * 20 + sx + 4];
            win[r][0] = a0.x; win[r][1] = a0.y; win[r][2] = a0.z; win[r][3] = a0.w;
            win[r][4] = a1.x; win[r][5] = a1.y; win[r][6] = a1.z; win[r][7] = a1.w;
        }

        const float* wrow = &w_lds[col * 25];
#pragma unroll
        for (int dy = 0; dy < 5; ++dy) {
#pragma unroll
            for (int dx = 0; dx < 5; ++dx) {
                float w = wrow[dy * 5 + dx];
#pragma unroll
                for (int p = 0; p < 4; ++p)
#pragma unroll
                    for (int q = 0; q < 4; ++q)
                        acc[(p << 2) + q] = fmaf(w, win[p + dy][q + dx], acc[(p << 2) + q]);
            }
        }
    }

    // epilogue: U = acc + bias - gamma*R ; S = (U > 1) ; flag near-threshold
    const float bv = bias[co];
    const int   plane = b * COUT + co;
    const float* Rp = R + (size_t)plane * HWHW;
    float* Sp = out + (size_t)plane * HWHW;
    float* Up = out + (size_t)NPIX + (size_t)plane * HWHW;
#pragma unroll
    for (int p = 0; p < 4; ++p) {
        int oy = ty0 + sy + p;
        int ro = (oy << 6) + tx0 + sx;
        float4 r4 = *(const float4*)&Rp[ro];
        float us[4];
        us[0] = acc[(p << 2) + 0] + bv - gamma * r4.x;
        us[1] = acc[(p << 2) + 1] + bv - gamma * r4.y;
        us[2] = acc[(p << 2) + 2] + bv - gamma * r4.z;
        us[3] = acc[(p << 2) + 3] + bv - gamma * r4.w;
        float4 uq = make_float4(us[0], us[1], us[2], us[3]);
        float4 sq = make_float4(us[0] > 1.f ? 1.f : 0.f,
                                us[1] > 1.f ? 1.f : 0.f,
                                us[2] > 1.f ? 1.f : 0.f,
                                us[3] > 1.f ? 1.f : 0.f);
        *(float4*)&Sp[ro] = sq;
        *(float4*)&Up[ro] = uq;
#pragma unroll
        for (int q = 0; q < 4; ++q) {
            if (fabsf(us[q] - 1.f) < TAU) {
                unsigned pos = atomicAdd(cnt, 1u);
                if (pos < (unsigned)cap)
                    list[pos] = (plane << 12) + ro + q;
            }
        }
    }
}

// ---------------------------------------------------------------------------
// Wave-parallel f64 repair: one wave per flagged element, lane = cin.
// Each lane does its cin's 25 taps; f64 shuffle reduction across 64 lanes.
// ---------------------------------------------------------------------------
__global__ __launch_bounds__(256) void repair_list_kernel(
    const float* __restrict__ P, const float* __restrict__ Q,
    const float* __restrict__ R, const float* __restrict__ W,
    const float* __restrict__ bias, float* __restrict__ out,
    const unsigned* __restrict__ cnt, const int* __restrict__ list, int cap,
    double alpha, double oma, double gamma)
{
    const int nrep = (int)min(*cnt, (unsigned)cap);
    const int wid  = (blockIdx.x * 256 + threadIdx.x) >> 6;
    const int lane = threadIdx.x & 63;           // = cin
    const int nw   = (gridDim.x * 256) >> 6;

    for (int i = wid; i < nrep; i += nw) {
        const int idx   = list[i];
        const int plane = idx >> 12;
        const int pix   = idx & 4095;
        const int oy    = pix >> 6;
        const int ox    = pix & 63;
        const int b     = plane >> 7;
        const int co    = plane & 127;

        const float* Pp = P + ((size_t)b * CIN + lane) * HWHW;
        const float* Qp = Q + ((size_t)b * CIN + lane) * HWHW;
        const float* Wp = W + ((size_t)co * CIN + lane) * 25;

        double acc = 0.0;
#pragma unroll
        for (int dy = 0; dy < 5; ++dy) {
            int iy = oy + dy - 2;
            if ((unsigned)iy >= 64u) continue;
#pragma unroll
            for (int dx = 0; dx < 5; ++dx) {
                int ix = ox + dx - 2;
                if ((unsigned)ix >= 64u) continue;
                int off = (iy << 6) + ix;
                double pn = alpha * (double)Pp[off] + oma * (double)Qp[off];
                acc = fma((double)Wp[dy * 5 + dx], pn, acc);
            }
        }
#pragma unroll
        for (int s = 32; s; s >>= 1) acc += __shfl_down(acc, s, 64);

        if (lane == 0) {
            double u64 = acc + (double)bias[co]
                       - gamma * (double)R[(size_t)plane * HWHW + pix];
            out[idx]                = (u64 > 1.0) ? 1.f : 0.f;
            out[(size_t)NPIX + idx] = (float)u64;
        }
    }
}

// readout init: ro[i] = 0.5 (the "+1)*0.5" constant term)
__global__ void ro_init(float* ro)
{
    int i = blockIdx.x * 256 + threadIdx.x;
    if (i < 640) ro[i] = 0.5f;
}

// ---------------------------------------------------------------------------
// readout[b][o] += 0.5 * sum_f maxpool(S)[b][f] * w_sign[o][f]
// ---------------------------------------------------------------------------
__global__ __launch_bounds__(256) void readout_kernel(
    const float* __restrict__ S, const float* __restrict__ wsig,
    float* __restrict__ ro)
{
    const int tid = threadIdx.x;
    const int b = blockIdx.x >> 7;
    const int c = blockIdx.x & 127;

    __shared__ float wl[10 * 1024];
    for (int idx = tid; idx < 10240; idx += 256) {
        int o = idx >> 10;
        int f = idx & 1023;
        wl[idx] = wsig[(size_t)o * 131072 + (c << 10) + f];
    }
    __syncthreads();

    float acc[10];
#pragma unroll
    for (int o = 0; o < 10; ++o) acc[o] = 0.f;

    const float* Sp = S + ((size_t)b * COUT + c) * HWHW;
#pragma unroll
    for (int i = 0; i < 4; ++i) {
        int fl = tid + (i << 8);               // 0..1023
        int ph = fl >> 5, pw = fl & 31;
        const float2 t0 = *(const float2*)&Sp[(ph << 7) + (pw << 1)];
        const float2 t1 = *(const float2*)&Sp[(ph << 7) + 64 + (pw << 1)];
        float m = fmaxf(fmaxf(t0.x, t0.y), fmaxf(t1.x, t1.y));
#pragma unroll
        for (int o = 0; o < 10; ++o)
            acc[o] = fmaf(m, wl[(o << 10) + fl], acc[o]);
    }

    __shared__ float part[4][10];
    const int wave = tid >> 6;
    const int lane = tid & 63;
#pragma unroll
    for (int o = 0; o < 10; ++o) {
        float v = acc[o];
        v += __shfl_down(v, 32, 64);
        v += __shfl_down(v, 16, 64);
        v += __shfl_down(v, 8, 64);
        v += __shfl_down(v, 4, 64);
        v += __shfl_down(v, 2, 64);
        v += __shfl_down(v, 1, 64);
        if (lane == 0) part[wave][o] = v;
    }
    __syncthreads();
    if (tid < 10) {
        float s = part[0][tid] + part[1][tid] + part[2][tid] + part[3][tid];
        atomicAdd(&ro[b * 10 + tid], 0.5f * s);
    }
}

extern "C" void kernel_launch(void* const* d_in, const int* in_sizes, int n_in,
                              void* d_out, int out_size, void* d_ws, size_t ws_size,
                              hipStream_t stream)
{
    // inputs: 0=input_t (UNUSED: Q_new is dead code), 1=P, 2=Q, 3=R,
    //         4=weights, 5=bias, 6=w_sign
    const float* P    = (const float*)d_in[1];
    const float* Q    = (const float*)d_in[2];
    const float* R    = (const float*)d_in[3];
    const float* W    = (const float*)d_in[4];
    const float* bias = (const float*)d_in[5];
    const float* wsig = (const float*)d_in[6];
    float* out = (float*)d_out;

    unsigned* cnt = (unsigned*)d_ws;
    int* list = (int*)((char*)d_ws + 16);
    size_t cap_sz = (ws_size > 16) ? (ws_size - 16) / 4 : 0;
    int cap = (int)(cap_sz > (size_t)NPIX ? (size_t)NPIX : cap_sz);

    const double alpha_d = exp(-1e-3 / 20e-3);
    const double oma_d   = 1.0 - alpha_d;
    const double gamma_d = exp(-1e-3 / 2.86e-3);

    hipMemsetAsync(d_ws, 0, 16, stream);   // zero repair counter

    dim3 grid(16, 8, 64);  // 16 spatial tiles x 8 cout groups x 64 batches
    lif_conv_kernel<<<grid, 256, 0, stream>>>(P, Q, R, W, bias, out,
                                              cnt, list, cap,
                                              (float)alpha_d, (float)oma_d,
                                              (float)gamma_d);

    repair_list_kernel<<<1024, 256, 0, stream>>>(P, Q, R, W, bias, out,
                                                 cnt, list, cap,
                                                 alpha_d, oma_d, gamma_d);

    float* ro = out + (size_t)2 * NPIX;
    ro_init<<<3, 256, 0, stream>>>(ro);
    readout_kernel<<<8192, 256, 0, stream>>>(out, wsig, ro);
}

// Round 4
// 1448.305 us; speedup vs baseline: 2.2913x; 1.3752x over previous
//
#include <hip/hip_runtime.h>
#include <math.h>

#define B_    64
#define CIN   64
#define COUT  128
#define HWHW  4096   // 64*64
#define NPIX  (B_ * COUT * HWHW)   // 33,554,432 per output map
#define TAU   1e-3f
#define NWELEM 204800              // 25*128*64 weight elems per plane

typedef _Float16 half8 __attribute__((ext_vector_type(8)));
typedef float    f32x4 __attribute__((ext_vector_type(4)));

// ---------------------------------------------------------------------------
// Weight pre-transform: W[cout][cin][5][5] f32 -> whi/wlo [tap][cout][cin] f16
// ---------------------------------------------------------------------------
__global__ __launch_bounds__(256) void wprep_kernel(
    const float* __restrict__ W, _Float16* __restrict__ whi,
    _Float16* __restrict__ wlo)
{
    int e = blockIdx.x * 256 + threadIdx.x;
    if (e >= NWELEM) return;
    int ci = e & 63;
    int co = (e >> 6) & 127;
    int t  = e >> 13;
    float w = W[(size_t)((co << 6) + ci) * 25 + t];
    _Float16 h = (_Float16)w;
    whi[e] = h;
    wlo[e] = (_Float16)(w - (float)h);
}

// ---------------------------------------------------------------------------
// MFMA conv: implicit GEMM, f16x2 split, 3 MFMA per K-step.
// Block: 256 thr (4 waves) = 16x16 spatial tile x 64 couts, one batch.
// cin chunked 2x32; input staged in LDS channels-last f16 hi/lo, XOR-swizzled.
// Wave w owns output rows 4w..4w+3 (4 M-tiles), all 4 N-tiles (16 couts each).
// ---------------------------------------------------------------------------
__global__ __launch_bounds__(256) void lif_conv_mfma_kernel(
    const float* __restrict__ P, const float* __restrict__ Q,
    const float* __restrict__ R, const _Float16* __restrict__ whi,
    const _Float16* __restrict__ wlo, const float* __restrict__ bias,
    float* __restrict__ out,
    unsigned* __restrict__ cnt, int* __restrict__ list, int cap,
    float alpha, float oma, float gamma)
{
    const int tid  = threadIdx.x;
    const int wave = tid >> 6;
    const int lane = tid & 63;
    const int b      = blockIdx.z;
    const int cobase = blockIdx.x << 6;          // 0 or 64
    const int ty0    = (blockIdx.y >> 2) << 4;
    const int tx0    = (blockIdx.y & 3) << 4;

    __shared__ _Float16 sH[12800];               // 400 px x 32 cin
    __shared__ _Float16 sL[12800];

    f32x4 acc[4][4];
#pragma unroll
    for (int i = 0; i < 4; ++i)
#pragma unroll
        for (int j = 0; j < 4; ++j) acc[i][j] = (f32x4){0.f, 0.f, 0.f, 0.f};

    const int ln15 = lane & 15;
    const int kgrp = lane >> 4;                  // 0..3

    for (int cc = 0; cc < 2; ++cc) {
        __syncthreads();
        // ---- stage 20x20 halo x 32 cin as f16 hi/lo, channels-last ----
        for (int e = tid; e < 512 * 32; e += 256) {
            int px = e & 511;
            if (px >= 400) continue;
            int ci = e >> 9;
            int r  = px / 20;
            int c_ = px - 20 * r;
            int gy = ty0 - 2 + r;
            int gx = tx0 - 2 + c_;
            float pn = 0.f;
            if ((unsigned)gy < 64u && (unsigned)gx < 64u) {
                size_t off = ((size_t)(b * CIN + (cc << 5) + ci) << 12)
                           + (gy << 6) + gx;
                pn = alpha * P[off] + oma * Q[off];
            }
            _Float16 h = (_Float16)pn;
            _Float16 l = (_Float16)(pn - (float)h);
            int a = (px << 6) + (ci << 1);
            a ^= (px & 3) << 4;                  // bank swizzle
            sH[a >> 1] = h;
            sL[a >> 1] = l;
        }
        __syncthreads();

        // ---- 25 taps, no barriers: B from global (L2), A from LDS ----
        for (int t = 0; t < 25; ++t) {
            const int dy = t / 5;
            const int dx = t - 5 * dy;

            half8 bH[4], bL[4];
#pragma unroll
            for (int nt = 0; nt < 4; ++nt) {
                size_t we = ((size_t)(t * COUT + cobase + (nt << 4) + ln15) << 6)
                          + (cc << 5) + (kgrp << 3);
                bH[nt] = *(const half8*)(whi + we);
                bL[nt] = *(const half8*)(wlo + we);
            }
#pragma unroll
            for (int mi = 0; mi < 4; ++mi) {
                const int r  = (wave << 2) + mi;
                const int hp = (r + dy) * 20 + dx + ln15;
                int a = (hp << 6) + (kgrp << 4);
                a ^= (hp & 3) << 4;
                half8 aH = *(const half8*)&sH[a >> 1];
                half8 aL = *(const half8*)&sL[a >> 1];
#pragma unroll
                for (int nt = 0; nt < 4; ++nt) {
                    acc[mi][nt] = __builtin_amdgcn_mfma_f32_16x16x32_f16(
                        aH, bH[nt], acc[mi][nt], 0, 0, 0);
                    acc[mi][nt] = __builtin_amdgcn_mfma_f32_16x16x32_f16(
                        aH, bL[nt], acc[mi][nt], 0, 0, 0);
                    acc[mi][nt] = __builtin_amdgcn_mfma_f32_16x16x32_f16(
                        aL, bH[nt], acc[mi][nt], 0, 0, 0);
                }
            }
        }
    }

    // ---- epilogue: U = acc + bias - gamma*R ; S = U>1 ; flag near-thr ----
    const int cb = kgrp << 2;                    // x-offset base (4 regs -> 4 x)
#pragma unroll
    for (int nt = 0; nt < 4; ++nt) {
        const int co = cobase + (nt << 4) + ln15;
        const float bv = bias[co];
        const size_t plane = (size_t)b * COUT + co;
#pragma unroll
        for (int mi = 0; mi < 4; ++mi) {
            const int oy = ty0 + (wave << 2) + mi;
            const size_t ro = (plane << 12) + (oy << 6) + tx0 + cb;
            float4 r4 = *(const float4*)&R[ro];
            float us[4];
            us[0] = acc[mi][nt][0] + bv - gamma * r4.x;
            us[1] = acc[mi][nt][1] + bv - gamma * r4.y;
            us[2] = acc[mi][nt][2] + bv - gamma * r4.z;
            us[3] = acc[mi][nt][3] + bv - gamma * r4.w;
            float4 uq = make_float4(us[0], us[1], us[2], us[3]);
            float4 sq = make_float4(us[0] > 1.f ? 1.f : 0.f,
                                    us[1] > 1.f ? 1.f : 0.f,
                                    us[2] > 1.f ? 1.f : 0.f,
                                    us[3] > 1.f ? 1.f : 0.f);
            *(float4*)&out[ro] = sq;
            *(float4*)&out[(size_t)NPIX + ro] = uq;
#pragma unroll
            for (int j = 0; j < 4; ++j) {
                if (fabsf(us[j] - 1.f) < TAU) {
                    unsigned pos = atomicAdd(cnt, 1u);
                    if (pos < (unsigned)cap)
                        list[pos] = (int)(ro + j);
                }
            }
        }
    }
}

// ---------------------------------------------------------------------------
// Wave-parallel f64 repair: one wave per flagged element, lane = cin.
// ---------------------------------------------------------------------------
__global__ __launch_bounds__(256) void repair_list_kernel(
    const float* __restrict__ P, const float* __restrict__ Q,
    const float* __restrict__ R, const float* __restrict__ W,
    const float* __restrict__ bias, float* __restrict__ out,
    const unsigned* __restrict__ cnt, const int* __restrict__ list, int cap,
    double alpha, double oma, double gamma)
{
    const int nrep = (int)min(*cnt, (unsigned)cap);
    const int wid  = (blockIdx.x * 256 + threadIdx.x) >> 6;
    const int lane = threadIdx.x & 63;           // = cin
    const int nw   = (gridDim.x * 256) >> 6;

    for (int i = wid; i < nrep; i += nw) {
        const int idx   = list[i];
        const int plane = idx >> 12;
        const int pix   = idx & 4095;
        const int oy    = pix >> 6;
        const int ox    = pix & 63;
        const int b     = plane >> 7;
        const int co    = plane & 127;

        const float* Pp = P + ((size_t)b * CIN + lane) * HWHW;
        const float* Qp = Q + ((size_t)b * CIN + lane) * HWHW;
        const float* Wp = W + ((size_t)co * CIN + lane) * 25;

        double acc = 0.0;
#pragma unroll
        for (int dy = 0; dy < 5; ++dy) {
            int iy = oy + dy - 2;
            if ((unsigned)iy >= 64u) continue;
#pragma unroll
            for (int dx = 0; dx < 5; ++dx) {
                int ix = ox + dx - 2;
                if ((unsigned)ix >= 64u) continue;
                int off = (iy << 6) + ix;
                double pn = alpha * (double)Pp[off] + oma * (double)Qp[off];
                acc = fma((double)Wp[dy * 5 + dx], pn, acc);
            }
        }
#pragma unroll
        for (int s = 32; s; s >>= 1) acc += __shfl_down(acc, s, 64);

        if (lane == 0) {
            double u64 = acc + (double)bias[co]
                       - gamma * (double)R[(size_t)plane * HWHW + pix];
            out[idx]                = (u64 > 1.0) ? 1.f : 0.f;
            out[(size_t)NPIX + idx] = (float)u64;
        }
    }
}

// readout init: ro[i] = 0.5 (the "+1)*0.5" constant term)
__global__ void ro_init(float* ro)
{
    int i = blockIdx.x * 256 + threadIdx.x;
    if (i < 640) ro[i] = 0.5f;
}

// ---------------------------------------------------------------------------
// readout[b][o] += 0.5 * sum_f maxpool(S)[b][f] * w_sign[o][f]
// ---------------------------------------------------------------------------
__global__ __launch_bounds__(256) void readout_kernel(
    const float* __restrict__ S, const float* __restrict__ wsig,
    float* __restrict__ ro)
{
    const int tid = threadIdx.x;
    const int b = blockIdx.x >> 7;
    const int c = blockIdx.x & 127;

    __shared__ float wl[10 * 1024];
    for (int idx = tid; idx < 10240; idx += 256) {
        int o = idx >> 10;
        int f = idx & 1023;
        wl[idx] = wsig[(size_t)o * 131072 + (c << 10) + f];
    }
    __syncthreads();

    float acc[10];
#pragma unroll
    for (int o = 0; o < 10; ++o) acc[o] = 0.f;

    const float* Sp = S + ((size_t)b * COUT + c) * HWHW;
#pragma unroll
    for (int i = 0; i < 4; ++i) {
        int fl = tid + (i << 8);               // 0..1023
        int ph = fl >> 5, pw = fl & 31;
        const float2 t0 = *(const float2*)&Sp[(ph << 7) + (pw << 1)];
        const float2 t1 = *(const float2*)&Sp[(ph << 7) + 64 + (pw << 1)];
        float m = fmaxf(fmaxf(t0.x, t0.y), fmaxf(t1.x, t1.y));
#pragma unroll
        for (int o = 0; o < 10; ++o)
            acc[o] = fmaf(m, wl[(o << 10) + fl], acc[o]);
    }

    __shared__ float part[4][10];
    const int wave = tid >> 6;
    const int lane = tid & 63;
#pragma unroll
    for (int o = 0; o < 10; ++o) {
        float v = acc[o];
        v += __shfl_down(v, 32, 64);
        v += __shfl_down(v, 16, 64);
        v += __shfl_down(v, 8, 64);
        v += __shfl_down(v, 4, 64);
        v += __shfl_down(v, 2, 64);
        v += __shfl_down(v, 1, 64);
        if (lane == 0) part[wave][o] = v;
    }
    __syncthreads();
    if (tid < 10) {
        float s = part[0][tid] + part[1][tid] + part[2][tid] + part[3][tid];
        atomicAdd(&ro[b * 10 + tid], 0.5f * s);
    }
}

extern "C" void kernel_launch(void* const* d_in, const int* in_sizes, int n_in,
                              void* d_out, int out_size, void* d_ws, size_t ws_size,
                              hipStream_t stream)
{
    // inputs: 0=input_t (UNUSED: Q_new is dead code), 1=P, 2=Q, 3=R,
    //         4=weights, 5=bias, 6=w_sign
    const float* P    = (const float*)d_in[1];
    const float* Q    = (const float*)d_in[2];
    const float* R    = (const float*)d_in[3];
    const float* W    = (const float*)d_in[4];
    const float* bias = (const float*)d_in[5];
    const float* wsig = (const float*)d_in[6];
    float* out = (float*)d_out;

    // d_ws layout: [0,16) counter | [16, 16+4*cap) repair list | tail: f16 weights
    const size_t wbytes = (size_t)NWELEM * 2 * 2;          // hi+lo planes
    size_t wsoff = (ws_size - wbytes) & ~(size_t)63;
    _Float16* whi = (_Float16*)((char*)d_ws + wsoff);
    _Float16* wlo = whi + NWELEM;
    unsigned* cnt = (unsigned*)d_ws;
    int* list = (int*)((char*)d_ws + 16);
    size_t cap_sz = (wsoff - 16) / 4;
    int cap = (int)(cap_sz > (size_t)NPIX ? (size_t)NPIX : cap_sz);

    const double alpha_d = exp(-1e-3 / 20e-3);
    const double oma_d   = 1.0 - alpha_d;
    const double gamma_d = exp(-1e-3 / 2.86e-3);

    hipMemsetAsync(d_ws, 0, 16, stream);   // zero repair counter

    wprep_kernel<<<(NWELEM + 255) / 256, 256, 0, stream>>>(W, whi, wlo);

    dim3 grid(2, 16, 64);  // cout-half x spatial tile x batch
    lif_conv_mfma_kernel<<<grid, 256, 0, stream>>>(P, Q, R, whi, wlo, bias, out,
                                                   cnt, list, cap,
                                                   (float)alpha_d, (float)oma_d,
                                                   (float)gamma_d);

    repair_list_kernel<<<1024, 256, 0, stream>>>(P, Q, R, W, bias, out,
                                                 cnt, list, cap,
                                                 alpha_d, oma_d, gamma_d);

    float* ro = out + (size_t)2 * NPIX;
    ro_init<<<3, 256, 0, stream>>>(ro);
    readout_kernel<<<8192, 256, 0, stream>>>(out, wsig, ro);
}

// Round 5
// 1443.576 us; speedup vs baseline: 2.2988x; 1.0033x over previous
//
#include <hip/hip_runtime.h>
#include <math.h>

#define B_    64
#define CIN   64
#define COUT  128
#define HWHW  4096   // 64*64
#define NPIX  (B_ * COUT * HWHW)   // 33,554,432 per output map
#define TAU   1e-3f
#define NWELEM 204800              // 25*128*64 weight elems per plane

typedef _Float16 half8 __attribute__((ext_vector_type(8)));
typedef float    f32x4 __attribute__((ext_vector_type(4)));

// ---------------------------------------------------------------------------
// Weight pre-transform: W[cout][cin][5][5] f32 -> whi/wlo [tap][cout][cin] f16
// ---------------------------------------------------------------------------
__global__ __launch_bounds__(256) void wprep_kernel(
    const float* __restrict__ W, _Float16* __restrict__ whi,
    _Float16* __restrict__ wlo)
{
    int e = blockIdx.x * 256 + threadIdx.x;
    if (e >= NWELEM) return;
    int ci = e & 63;
    int co = (e >> 6) & 127;
    int t  = e >> 13;
    float w = W[(size_t)((co << 6) + ci) * 25 + t];
    _Float16 h = (_Float16)w;
    whi[e] = h;
    wlo[e] = (_Float16)(w - (float)h);
}

// ---------------------------------------------------------------------------
// MFMA conv: implicit GEMM, f16x2 split, 3 MFMA per K-step.
// Block: 256 thr (4 waves) = 16x16 spatial tile x 64 couts, one batch.
// cin chunked 2x32; input staged in LDS channels-last f16 hi/lo, XOR-swizzled.
// Wave w owns output rows 4w..4w+3 (4 M-tiles), all 4 N-tiles (16 couts each).
// ---------------------------------------------------------------------------
__global__ __launch_bounds__(256) void lif_conv_mfma_kernel(
    const float* __restrict__ P, const float* __restrict__ Q,
    const float* __restrict__ R, const _Float16* __restrict__ whi,
    const _Float16* __restrict__ wlo, const float* __restrict__ bias,
    float* __restrict__ out,
    unsigned* __restrict__ cnt, int* __restrict__ list, int cap,
    float alpha, float oma, float gamma)
{
    const int tid  = threadIdx.x;
    const int wave = tid >> 6;
    const int lane = tid & 63;
    const int b      = blockIdx.z;
    const int cobase = blockIdx.x << 6;          // 0 or 64
    const int ty0    = (blockIdx.y >> 2) << 4;
    const int tx0    = (blockIdx.y & 3) << 4;

    __shared__ _Float16 sH[12800];               // 400 px x 32 cin
    __shared__ _Float16 sL[12800];

    f32x4 acc[4][4];
#pragma unroll
    for (int i = 0; i < 4; ++i)
#pragma unroll
        for (int j = 0; j < 4; ++j) acc[i][j] = (f32x4){0.f, 0.f, 0.f, 0.f};

    const int ln15 = lane & 15;
    const int kgrp = lane >> 4;                  // 0..3

    for (int cc = 0; cc < 2; ++cc) {
        __syncthreads();
        // ---- stage 20x20 halo x 32 cin as f16 hi/lo, channels-last ----
        for (int e = tid; e < 512 * 32; e += 256) {
            int px = e & 511;
            if (px >= 400) continue;
            int ci = e >> 9;
            int r  = px / 20;
            int c_ = px - 20 * r;
            int gy = ty0 - 2 + r;
            int gx = tx0 - 2 + c_;
            float pn = 0.f;
            if ((unsigned)gy < 64u && (unsigned)gx < 64u) {
                size_t off = ((size_t)(b * CIN + (cc << 5) + ci) << 12)
                           + (gy << 6) + gx;
                pn = alpha * P[off] + oma * Q[off];
            }
            _Float16 h = (_Float16)pn;
            _Float16 l = (_Float16)(pn - (float)h);
            int a = (px << 6) + (ci << 1);
            a ^= (px & 3) << 4;                  // bank swizzle
            sH[a >> 1] = h;
            sL[a >> 1] = l;
        }
        __syncthreads();

        // ---- 25 taps, no barriers: B from global (L2), A from LDS ----
        for (int t = 0; t < 25; ++t) {
            const int dy = t / 5;
            const int dx = t - 5 * dy;

            half8 bH[4], bL[4];
#pragma unroll
            for (int nt = 0; nt < 4; ++nt) {
                size_t we = ((size_t)(t * COUT + cobase + (nt << 4) + ln15) << 6)
                          + (cc << 5) + (kgrp << 3);
                bH[nt] = *(const half8*)(whi + we);
                bL[nt] = *(const half8*)(wlo + we);
            }
#pragma unroll
            for (int mi = 0; mi < 4; ++mi) {
                const int r  = (wave << 2) + mi;
                const int hp = (r + dy) * 20 + dx + ln15;
                int a = (hp << 6) + (kgrp << 4);
                a ^= (hp & 3) << 4;
                half8 aH = *(const half8*)&sH[a >> 1];
                half8 aL = *(const half8*)&sL[a >> 1];
#pragma unroll
                for (int nt = 0; nt < 4; ++nt) {
                    acc[mi][nt] = __builtin_amdgcn_mfma_f32_16x16x32_f16(
                        aH, bH[nt], acc[mi][nt], 0, 0, 0);
                    acc[mi][nt] = __builtin_amdgcn_mfma_f32_16x16x32_f16(
                        aH, bL[nt], acc[mi][nt], 0, 0, 0);
                    acc[mi][nt] = __builtin_amdgcn_mfma_f32_16x16x32_f16(
                        aL, bH[nt], acc[mi][nt], 0, 0, 0);
                }
            }
        }
    }

    // ---- epilogue: U = acc + bias - gamma*R ; S = U>1 ; flag near-thr ----
    const int cb = kgrp << 2;                    // x-offset base (4 regs -> 4 x)
#pragma unroll
    for (int nt = 0; nt < 4; ++nt) {
        const int co = cobase + (nt << 4) + ln15;
        const float bv = bias[co];
        const size_t plane = (size_t)b * COUT + co;
#pragma unroll
        for (int mi = 0; mi < 4; ++mi) {
            const int oy = ty0 + (wave << 2) + mi;
            const size_t ro = (plane << 12) + (oy << 6) + tx0 + cb;
            float4 r4 = *(const float4*)&R[ro];
            float us[4];
            us[0] = acc[mi][nt][0] + bv - gamma * r4.x;
            us[1] = acc[mi][nt][1] + bv - gamma * r4.y;
            us[2] = acc[mi][nt][2] + bv - gamma * r4.z;
            us[3] = acc[mi][nt][3] + bv - gamma * r4.w;
            float4 uq = make_float4(us[0], us[1], us[2], us[3]);
            float4 sq = make_float4(us[0] > 1.f ? 1.f : 0.f,
                                    us[1] > 1.f ? 1.f : 0.f,
                                    us[2] > 1.f ? 1.f : 0.f,
                                    us[3] > 1.f ? 1.f : 0.f);
            *(float4*)&out[ro] = sq;
            *(float4*)&out[(size_t)NPIX + ro] = uq;
#pragma unroll
            for (int j = 0; j < 4; ++j) {
                if (fabsf(us[j] - 1.f) < TAU) {
                    unsigned pos = atomicAdd(cnt, 1u);
                    if (pos < (unsigned)cap)
                        list[pos] = (int)(ro + j);
                }
            }
        }
    }
}

// ---------------------------------------------------------------------------
// Wave-parallel f64 repair: one wave per flagged element, lane = cin.
// ---------------------------------------------------------------------------
__global__ __launch_bounds__(256) void repair_list_kernel(
    const float* __restrict__ P, const float* __restrict__ Q,
    const float* __restrict__ R, const float* __restrict__ W,
    const float* __restrict__ bias, float* __restrict__ out,
    const unsigned* __restrict__ cnt, const int* __restrict__ list, int cap,
    double alpha, double oma, double gamma)
{
    const int nrep = (int)min(*cnt, (unsigned)cap);
    const int wid  = (blockIdx.x * 256 + threadIdx.x) >> 6;
    const int lane = threadIdx.x & 63;           // = cin
    const int nw   = (gridDim.x * 256) >> 6;

    for (int i = wid; i < nrep; i += nw) {
        const int idx   = list[i];
        const int plane = idx >> 12;
        const int pix   = idx & 4095;
        const int oy    = pix >> 6;
        const int ox    = pix & 63;
        const int b     = plane >> 7;
        const int co    = plane & 127;

        const float* Pp = P + ((size_t)b * CIN + lane) * HWHW;
        const float* Qp = Q + ((size_t)b * CIN + lane) * HWHW;
        const float* Wp = W + ((size_t)co * CIN + lane) * 25;

        double acc = 0.0;
#pragma unroll
        for (int dy = 0; dy < 5; ++dy) {
            int iy = oy + dy - 2;
            if ((unsigned)iy >= 64u) continue;
#pragma unroll
            for (int dx = 0; dx < 5; ++dx) {
                int ix = ox + dx - 2;
                if ((unsigned)ix >= 64u) continue;
                int off = (iy << 6) + ix;
                double pn = alpha * (double)Pp[off] + oma * (double)Qp[off];
                acc = fma((double)Wp[dy * 5 + dx], pn, acc);
            }
        }
#pragma unroll
        for (int s = 32; s; s >>= 1) acc += __shfl_down(acc, s, 64);

        if (lane == 0) {
            double u64 = acc + (double)bias[co]
                       - gamma * (double)R[(size_t)plane * HWHW + pix];
            out[idx]                = (u64 > 1.0) ? 1.f : 0.f;
            out[(size_t)NPIX + idx] = (float)u64;
        }
    }
}

// readout init: ro[i] = 0.5 (the "+1)*0.5" constant term)
__global__ void ro_init(float* ro)
{
    int i = blockIdx.x * 256 + threadIdx.x;
    if (i < 640) ro[i] = 0.5f;
}

// ---------------------------------------------------------------------------
// readout[b][o] += 0.5 * sum_f maxpool(S)[b][f] * w_sign[o][f]
// ---------------------------------------------------------------------------
__global__ __launch_bounds__(256) void readout_kernel(
    const float* __restrict__ S, const float* __restrict__ wsig,
    float* __restrict__ ro)
{
    const int tid = threadIdx.x;
    const int b = blockIdx.x >> 7;
    const int c = blockIdx.x & 127;

    __shared__ float wl[10 * 1024];
    for (int idx = tid; idx < 10240; idx += 256) {
        int o = idx >> 10;
        int f = idx & 1023;
        wl[idx] = wsig[(size_t)o * 131072 + (c << 10) + f];
    }
    __syncthreads();

    float acc[10];
#pragma unroll
    for (int o = 0; o < 10; ++o) acc[o] = 0.f;

    const float* Sp = S + ((size_t)b * COUT + c) * HWHW;
#pragma unroll
    for (int i = 0; i < 4; ++i) {
        int fl = tid + (i << 8);               // 0..1023
        int ph = fl >> 5, pw = fl & 31;
        const float2 t0 = *(const float2*)&Sp[(ph << 7) + (pw << 1)];
        const float2 t1 = *(const float2*)&Sp[(ph << 7) + 64 + (pw << 1)];
        float m = fmaxf(fmaxf(t0.x, t0.y), fmaxf(t1.x, t1.y));
#pragma unroll
        for (int o = 0; o < 10; ++o)
            acc[o] = fmaf(m, wl[(o << 10) + fl], acc[o]);
    }

    __shared__ float part[4][10];
    const int wave = tid >> 6;
    const int lane = tid & 63;
#pragma unroll
    for (int o = 0; o < 10; ++o) {
        float v = acc[o];
        v += __shfl_down(v, 32, 64);
        v += __shfl_down(v, 16, 64);
        v += __shfl_down(v, 8, 64);
        v += __shfl_down(v, 4, 64);
        v += __shfl_down(v, 2, 64);
        v += __shfl_down(v, 1, 64);
        if (lane == 0) part[wave][o] = v;
    }
    __syncthreads();
    if (tid < 10) {
        float s = part[0][tid] + part[1][tid] + part[2][tid] + part[3][tid];
        atomicAdd(&ro[b * 10 + tid], 0.5f * s);
    }
}

extern "C" void kernel_launch(void* const* d_in, const int* in_sizes, int n_in,
                              void* d_out, int out_size, void* d_ws, size_t ws_size,
                              hipStream_t stream)
{
    // inputs: 0=input_t (UNUSED: Q_new is dead code), 1=P, 2=Q, 3=R,
    //         4=weights, 5=bias, 6=w_sign
    const float* P    = (const float*)d_in[1];
    const float* Q    = (const float*)d_in[2];
    const float* R    = (const float*)d_in[3];
    const float* W    = (const float*)d_in[4];
    const float* bias = (const float*)d_in[5];
    const float* wsig = (const float*)d_in[6];
    float* out = (float*)d_out;

    // d_ws layout: [0,16) counter | [16, 16+4*cap) repair list | tail: f16 weights
    const size_t wbytes = (size_t)NWELEM * 2 * 2;          // hi+lo planes
    size_t wsoff = (ws_size - wbytes) & ~(size_t)63;
    _Float16* whi = (_Float16*)((char*)d_ws + wsoff);
    _Float16* wlo = whi + NWELEM;
    unsigned* cnt = (unsigned*)d_ws;
    int* list = (int*)((char*)d_ws + 16);
    size_t cap_sz = (wsoff - 16) / 4;
    int cap = (int)(cap_sz > (size_t)NPIX ? (size_t)NPIX : cap_sz);

    const double alpha_d = exp(-1e-3 / 20e-3);
    const double oma_d   = 1.0 - alpha_d;
    const double gamma_d = exp(-1e-3 / 2.86e-3);

    hipMemsetAsync(d_ws, 0, 16, stream);   // zero repair counter

    wprep_kernel<<<(NWELEM + 255) / 256, 256, 0, stream>>>(W, whi, wlo);

    dim3 grid(2, 16, 64);  // cout-half x spatial tile x batch
    lif_conv_mfma_kernel<<<grid, 256, 0, stream>>>(P, Q, R, whi, wlo, bias, out,
                                                   cnt, list, cap,
                                                   (float)alpha_d, (float)oma_d,
                                                   (float)gamma_d);

    repair_list_kernel<<<1024, 256, 0, stream>>>(P, Q, R, W, bias, out,
                                                 cnt, list, cap,
                                                 alpha_d, oma_d, gamma_d);

    float* ro = out + (size_t)2 * NPIX;
    ro_init<<<3, 256, 0, stream>>>(ro);
    readout_kernel<<<8192, 256, 0, stream>>>(out, wsig, ro);
}

// Round 6
// 819.503 us; speedup vs baseline: 4.0494x; 1.7615x over previous
//
#include <hip/hip_runtime.h>
#include <math.h>

#define B_    64
#define CIN   64
#define COUT  128
#define HWHW  4096   // 64*64
#define NPIX  (B_ * COUT * HWHW)   // 33,554,432 per output map
#define TAU   3e-4f
#define NWELEM 204800              // 25*128*64 weight elems per plane
#define POOLED_FLOATS (B_ * COUT * 1024)   // 8,388,608

typedef _Float16 half8 __attribute__((ext_vector_type(8)));
typedef float    f32x4 __attribute__((ext_vector_type(4)));

// ---------------------------------------------------------------------------
// Weight pre-transform: W[cout][cin][5][5] f32 -> whi/wlo [tap][cout][cin] f16
// ---------------------------------------------------------------------------
__global__ __launch_bounds__(256) void wprep_kernel(
    const float* __restrict__ W, _Float16* __restrict__ whi,
    _Float16* __restrict__ wlo)
{
    int e = blockIdx.x * 256 + threadIdx.x;
    if (e >= NWELEM) return;
    int ci = e & 63;
    int co = (e >> 6) & 127;
    int t  = e >> 13;
    float w = W[(size_t)((co << 6) + ci) * 25 + t];
    _Float16 h = (_Float16)w;
    whi[e] = h;
    wlo[e] = (_Float16)(w - (float)h);
}

// ---------------------------------------------------------------------------
// MFMA conv, round-6 edition:
//  - weight register double-buffer (prefetch tap t+1 during tap t MFMAs)
//  - LDS swizzle a ^= (px&7)<<4, identical formula on b128 writes and reads
//  - 2x2 maxpool fused into epilogue -> pooled[plane][32][32] in d_ws
// ---------------------------------------------------------------------------
struct WFrag { half8 h[4]; half8 l[4]; };

__device__ __forceinline__ void load_wfrag(WFrag& w, const _Float16* __restrict__ whi,
                                           const _Float16* __restrict__ wlo,
                                           size_t wb, int t)
{
    const _Float16* ph = whi + wb + (size_t)t * 8192;
    const _Float16* pl = wlo + wb + (size_t)t * 8192;
#pragma unroll
    for (int nt = 0; nt < 4; ++nt) {
        w.h[nt] = *(const half8*)(ph + (nt << 10));
        w.l[nt] = *(const half8*)(pl + (nt << 10));
    }
}

__device__ __forceinline__ void mfma_tap(f32x4 acc[4][4],
                                         const _Float16* __restrict__ sH,
                                         const _Float16* __restrict__ sL,
                                         const WFrag& w, int t,
                                         int wave, int ln15, int kgrp)
{
    const int dy = t / 5;
    const int dx = t - 5 * dy;
#pragma unroll
    for (int mi = 0; mi < 4; ++mi) {
        const int hp = ((wave << 2) + mi + dy) * 20 + dx + ln15;
        int a = (hp << 6) + (kgrp << 4);
        a ^= (hp & 7) << 4;
        half8 aH = *(const half8*)&sH[a >> 1];
        half8 aL = *(const half8*)&sL[a >> 1];
#pragma unroll
        for (int nt = 0; nt < 4; ++nt) {
            acc[mi][nt] = __builtin_amdgcn_mfma_f32_16x16x32_f16(
                aH, w.h[nt], acc[mi][nt], 0, 0, 0);
            acc[mi][nt] = __builtin_amdgcn_mfma_f32_16x16x32_f16(
                aH, w.l[nt], acc[mi][nt], 0, 0, 0);
            acc[mi][nt] = __builtin_amdgcn_mfma_f32_16x16x32_f16(
                aL, w.h[nt], acc[mi][nt], 0, 0, 0);
        }
    }
}

__global__ __launch_bounds__(256, 3) void lif_conv_mfma_kernel(
    const float* __restrict__ P, const float* __restrict__ Q,
    const float* __restrict__ R, const _Float16* __restrict__ whi,
    const _Float16* __restrict__ wlo, const float* __restrict__ bias,
    float* __restrict__ out, float* __restrict__ pooled,
    unsigned* __restrict__ cnt, int* __restrict__ list, int cap, int do_pool,
    float alpha, float oma, float gamma)
{
    const int tid  = threadIdx.x;
    const int wave = tid >> 6;
    const int lane = tid & 63;
    const int b      = blockIdx.z;
    const int cobase = blockIdx.x << 6;          // 0 or 64
    const int ty0    = (blockIdx.y >> 2) << 4;
    const int tx0    = (blockIdx.y & 3) << 4;
    const int ln15   = lane & 15;
    const int kgrp   = lane >> 4;                // 0..3

    __shared__ __align__(16) _Float16 sH[12800];   // 400 px x 32 cin
    __shared__ __align__(16) _Float16 sL[12800];

    f32x4 acc[4][4];
#pragma unroll
    for (int i = 0; i < 4; ++i)
#pragma unroll
        for (int j = 0; j < 4; ++j) acc[i][j] = (f32x4){0.f, 0.f, 0.f, 0.f};

    // per-lane weight base: [tap][cout][cin] elems; + t*8192 + nt*1024 later
    const size_t wb = ((size_t)(cobase + ln15) << 6) + (kgrp << 3);

    for (int cc = 0; cc < 2; ++cc) {
        __syncthreads();
        // ---- stage 20x20 halo x 32 cin: one b128 write per (px, 8-cin) ----
        for (int e = tid; e < 2048; e += 256) {
            int px   = e & 511;
            int koct = e >> 9;                   // 0..3 (8 cins each)
            if (px >= 400) continue;
            int r  = px / 20;
            int c_ = px - 20 * r;
            int gy = ty0 - 2 + r;
            int gx = tx0 - 2 + c_;
            half8 hv, lv;
            if ((unsigned)gy < 64u && (unsigned)gx < 64u) {
                const float* Pp = P + (((size_t)(b * CIN + (cc << 5) + (koct << 3))) << 12)
                                + (gy << 6) + gx;
                const float* Qp = Q + (((size_t)(b * CIN + (cc << 5) + (koct << 3))) << 12)
                                + (gy << 6) + gx;
#pragma unroll
                for (int j = 0; j < 8; ++j) {
                    float pn = alpha * Pp[j << 12] + oma * Qp[j << 12];
                    _Float16 h = (_Float16)pn;
                    hv[j] = h;
                    lv[j] = (_Float16)(pn - (float)h);
                }
            } else {
#pragma unroll
                for (int j = 0; j < 8; ++j) { hv[j] = (_Float16)0.f; lv[j] = (_Float16)0.f; }
            }
            int a = (px << 6) + (koct << 4);
            a ^= (px & 7) << 4;                  // same swizzle as reads
            *(half8*)&sH[a >> 1] = hv;
            *(half8*)&sL[a >> 1] = lv;
        }
        __syncthreads();

        // ---- 25 taps, weight register double-buffer ----
        const size_t wbc = wb + (cc << 5);
        WFrag w0, w1;
        load_wfrag(w0, whi, wlo, wbc, 0);
        for (int t2 = 0; t2 < 12; ++t2) {
            load_wfrag(w1, whi, wlo, wbc, 2 * t2 + 1);
            mfma_tap(acc, sH, sL, w0, 2 * t2, wave, ln15, kgrp);
            load_wfrag(w0, whi, wlo, wbc, 2 * t2 + 2);
            mfma_tap(acc, sH, sL, w1, 2 * t2 + 1, wave, ln15, kgrp);
        }
        mfma_tap(acc, sH, sL, w0, 24, wave, ln15, kgrp);
    }

    // ---- epilogue: U, S, near-threshold flag, fused 2x2 pool ----
    const int cb = kgrp << 2;
#pragma unroll
    for (int nt = 0; nt < 4; ++nt) {
        const int co = cobase + (nt << 4) + ln15;
        const float bv = bias[co];
        const int plane = b * COUT + co;
        float us[4][4];
#pragma unroll
        for (int mi = 0; mi < 4; ++mi) {
            const int oy = ty0 + (wave << 2) + mi;
            const size_t ro = ((size_t)plane << 12) + (oy << 6) + tx0 + cb;
            float4 r4 = *(const float4*)&R[ro];
            us[mi][0] = acc[mi][nt][0] + bv - gamma * r4.x;
            us[mi][1] = acc[mi][nt][1] + bv - gamma * r4.y;
            us[mi][2] = acc[mi][nt][2] + bv - gamma * r4.z;
            us[mi][3] = acc[mi][nt][3] + bv - gamma * r4.w;
            float4 uq = make_float4(us[mi][0], us[mi][1], us[mi][2], us[mi][3]);
            float4 sq = make_float4(us[mi][0] > 1.f ? 1.f : 0.f,
                                    us[mi][1] > 1.f ? 1.f : 0.f,
                                    us[mi][2] > 1.f ? 1.f : 0.f,
                                    us[mi][3] > 1.f ? 1.f : 0.f);
            *(float4*)&out[ro] = sq;
            *(float4*)&out[(size_t)NPIX + ro] = uq;
#pragma unroll
            for (int j = 0; j < 4; ++j) {
                if (fabsf(us[mi][j] - 1.f) < TAU) {
                    unsigned pos = atomicAdd(cnt, 1u);
                    if (pos < (unsigned)cap)
                        list[pos] = (int)(ro + j);
                }
            }
        }
        if (do_pool) {
            const int poy = (ty0 + (wave << 2)) >> 1;
            const int pox = (tx0 + cb) >> 1;
            float* pp = pooled + ((size_t)plane << 10) + (poy << 5) + pox;
            float2 p0, p1;
            p0.x = (fmaxf(fmaxf(us[0][0], us[0][1]), fmaxf(us[1][0], us[1][1])) > 1.f) ? 1.f : 0.f;
            p0.y = (fmaxf(fmaxf(us[0][2], us[0][3]), fmaxf(us[1][2], us[1][3])) > 1.f) ? 1.f : 0.f;
            p1.x = (fmaxf(fmaxf(us[2][0], us[2][1]), fmaxf(us[3][0], us[3][1])) > 1.f) ? 1.f : 0.f;
            p1.y = (fmaxf(fmaxf(us[2][2], us[2][3]), fmaxf(us[3][2], us[3][3])) > 1.f) ? 1.f : 0.f;
            *(float2*)pp = p0;
            *(float2*)(pp + 32) = p1;
        }
    }
}

// ---------------------------------------------------------------------------
// Wave-parallel f64 repair: one wave per flagged element, lane = cin.
// ---------------------------------------------------------------------------
__global__ __launch_bounds__(256) void repair_list_kernel(
    const float* __restrict__ P, const float* __restrict__ Q,
    const float* __restrict__ R, const float* __restrict__ W,
    const float* __restrict__ bias, float* __restrict__ out,
    const unsigned* __restrict__ cnt, const int* __restrict__ list, int cap,
    double alpha, double oma, double gamma)
{
    const int nrep = (int)min(*cnt, (unsigned)cap);
    const int wid  = (blockIdx.x * 256 + threadIdx.x) >> 6;
    const int lane = threadIdx.x & 63;           // = cin
    const int nw   = (gridDim.x * 256) >> 6;

    for (int i = wid; i < nrep; i += nw) {
        const int idx   = list[i];
        const int plane = idx >> 12;
        const int pix   = idx & 4095;
        const int oy    = pix >> 6;
        const int ox    = pix & 63;
        const int b     = plane >> 7;
        const int co    = plane & 127;

        const float* Pp = P + ((size_t)b * CIN + lane) * HWHW;
        const float* Qp = Q + ((size_t)b * CIN + lane) * HWHW;
        const float* Wp = W + ((size_t)co * CIN + lane) * 25;

        double acc = 0.0;
#pragma unroll
        for (int dy = 0; dy < 5; ++dy) {
            int iy = oy + dy - 2;
            if ((unsigned)iy >= 64u) continue;
#pragma unroll
            for (int dx = 0; dx < 5; ++dx) {
                int ix = ox + dx - 2;
                if ((unsigned)ix >= 64u) continue;
                int off = (iy << 6) + ix;
                double pn = alpha * (double)Pp[off] + oma * (double)Qp[off];
                acc = fma((double)Wp[dy * 5 + dx], pn, acc);
            }
        }
#pragma unroll
        for (int s = 32; s; s >>= 1) acc += __shfl_down(acc, s, 64);

        if (lane == 0) {
            double u64 = acc + (double)bias[co]
                       - gamma * (double)R[(size_t)plane * HWHW + pix];
            out[idx]                = (u64 > 1.0) ? 1.f : 0.f;
            out[(size_t)NPIX + idx] = (float)u64;
        }
    }
}

// ---------------------------------------------------------------------------
// Re-pool the 2x2 groups of repaired elements from final S (idempotent).
// ---------------------------------------------------------------------------
__global__ __launch_bounds__(256) void pool_fix_kernel(
    const float* __restrict__ out, float* __restrict__ pooled,
    const unsigned* __restrict__ cnt, const int* __restrict__ list, int cap)
{
    const int nrep = (int)min(*cnt, (unsigned)cap);
    for (int i = blockIdx.x * 256 + threadIdx.x; i < nrep; i += gridDim.x * 256) {
        int idx   = list[i];
        int plane = idx >> 12;
        int pix   = idx & 4095;
        int oy    = pix >> 6;
        int ox    = pix & 63;
        size_t base = ((size_t)plane << 12) + ((oy & ~1) << 6) + (ox & ~1);
        float m = fmaxf(fmaxf(out[base], out[base + 1]),
                        fmaxf(out[base + 64], out[base + 65]));
        pooled[((size_t)plane << 10) + ((oy >> 1) << 5) + (ox >> 1)] = m;
    }
}

// readout init: ro[i] = 0.5 (the "+1)*0.5" constant term)
__global__ void ro_init(float* ro)
{
    int i = blockIdx.x * 256 + threadIdx.x;
    if (i < 640) ro[i] = 0.5f;
}

// ---------------------------------------------------------------------------
// readout from pooled buffer: block = (channel c, batch-group of 8).
// wsig chunk staged once per block, amortized over 8 batches.
// ---------------------------------------------------------------------------
__global__ __launch_bounds__(256) void readout_pooled_kernel(
    const float* __restrict__ pooled, const float* __restrict__ wsig,
    float* __restrict__ ro)
{
    const int tid = threadIdx.x;
    const int c   = blockIdx.x;          // 0..127
    const int bg  = blockIdx.y;          // 0..7

    __shared__ float wl[10 * 1024];
    for (int i = tid; i < 10240; i += 256)
        wl[i] = wsig[(size_t)(i >> 10) * 131072 + (c << 10) + (i & 1023)];
    __syncthreads();

    __shared__ float part[4][10];
    const int wave = tid >> 6;
    const int lane = tid & 63;

    for (int bi = 0; bi < 8; ++bi) {
        const int b = (bg << 3) + bi;
        const float* pp = pooled + (((size_t)b * COUT + c) << 10);
        float acc[10];
#pragma unroll
        for (int o = 0; o < 10; ++o) acc[o] = 0.f;
#pragma unroll
        for (int it = 0; it < 4; ++it) {
            int f = tid + (it << 8);
            float m = pp[f];
#pragma unroll
            for (int o = 0; o < 10; ++o)
                acc[o] = fmaf(m, wl[(o << 10) + f], acc[o]);
        }
#pragma unroll
        for (int o = 0; o < 10; ++o) {
            float v = acc[o];
            v += __shfl_down(v, 32, 64);
            v += __shfl_down(v, 16, 64);
            v += __shfl_down(v, 8, 64);
            v += __shfl_down(v, 4, 64);
            v += __shfl_down(v, 2, 64);
            v += __shfl_down(v, 1, 64);
            if (lane == 0) part[wave][o] = v;
        }
        __syncthreads();
        if (tid < 10) {
            float s = part[0][tid] + part[1][tid] + part[2][tid] + part[3][tid];
            atomicAdd(&ro[b * 10 + tid], 0.5f * s);
        }
        __syncthreads();
    }
}

// ---------------------------------------------------------------------------
// Fallback readout reading S directly (used if ws_size too small for pooled).
// ---------------------------------------------------------------------------
__global__ __launch_bounds__(256) void readout_kernel(
    const float* __restrict__ S, const float* __restrict__ wsig,
    float* __restrict__ ro)
{
    const int tid = threadIdx.x;
    const int b = blockIdx.x >> 7;
    const int c = blockIdx.x & 127;

    __shared__ float wl[10 * 1024];
    for (int idx = tid; idx < 10240; idx += 256) {
        int o = idx >> 10;
        int f = idx & 1023;
        wl[idx] = wsig[(size_t)o * 131072 + (c << 10) + f];
    }
    __syncthreads();

    float acc[10];
#pragma unroll
    for (int o = 0; o < 10; ++o) acc[o] = 0.f;

    const float* Sp = S + ((size_t)b * COUT + c) * HWHW;
#pragma unroll
    for (int i = 0; i < 4; ++i) {
        int fl = tid + (i << 8);
        int ph = fl >> 5, pw = fl & 31;
        const float2 t0 = *(const float2*)&Sp[(ph << 7) + (pw << 1)];
        const float2 t1 = *(const float2*)&Sp[(ph << 7) + 64 + (pw << 1)];
        float m = fmaxf(fmaxf(t0.x, t0.y), fmaxf(t1.x, t1.y));
#pragma unroll
        for (int o = 0; o < 10; ++o)
            acc[o] = fmaf(m, wl[(o << 10) + fl], acc[o]);
    }

    __shared__ float part[4][10];
    const int wave = tid >> 6;
    const int lane = tid & 63;
#pragma unroll
    for (int o = 0; o < 10; ++o) {
        float v = acc[o];
        v += __shfl_down(v, 32, 64);
        v += __shfl_down(v, 16, 64);
        v += __shfl_down(v, 8, 64);
        v += __shfl_down(v, 4, 64);
        v += __shfl_down(v, 2, 64);
        v += __shfl_down(v, 1, 64);
        if (lane == 0) part[wave][o] = v;
    }
    __syncthreads();
    if (tid < 10) {
        float s = part[0][tid] + part[1][tid] + part[2][tid] + part[3][tid];
        atomicAdd(&ro[b * 10 + tid], 0.5f * s);
    }
}

extern "C" void kernel_launch(void* const* d_in, const int* in_sizes, int n_in,
                              void* d_out, int out_size, void* d_ws, size_t ws_size,
                              hipStream_t stream)
{
    // inputs: 0=input_t (UNUSED: Q_new is dead code), 1=P, 2=Q, 3=R,
    //         4=weights, 5=bias, 6=w_sign
    const float* P    = (const float*)d_in[1];
    const float* Q    = (const float*)d_in[2];
    const float* R    = (const float*)d_in[3];
    const float* W    = (const float*)d_in[4];
    const float* bias = (const float*)d_in[5];
    const float* wsig = (const float*)d_in[6];
    float* out = (float*)d_out;

    // d_ws layout: [0,16) counter | [64, 64+33.5MB) pooled | list | f16 weights tail
    const size_t wbytes = (size_t)NWELEM * 2 * 2;          // hi+lo planes
    size_t wsoff = (ws_size - wbytes) & ~(size_t)63;
    _Float16* whi = (_Float16*)((char*)d_ws + wsoff);
    _Float16* wlo = whi + NWELEM;
    unsigned* cnt = (unsigned*)d_ws;

    const size_t pooled_bytes = (size_t)POOLED_FLOATS * 4;  // 33,554,432
    const int use_pooled = ws_size >= 64 + pooled_bytes + (1u << 22) + wbytes + 64;
    float* pooled = use_pooled ? (float*)((char*)d_ws + 64) : (float*)d_ws;
    size_t listoff = use_pooled ? (64 + pooled_bytes) : 16;
    int* list = (int*)((char*)d_ws + listoff);
    size_t cap_sz = (wsoff > listoff) ? (wsoff - listoff) / 4 : 0;
    int cap = (int)(cap_sz > (size_t)NPIX ? (size_t)NPIX : cap_sz);

    const double alpha_d = exp(-1e-3 / 20e-3);
    const double oma_d   = 1.0 - alpha_d;
    const double gamma_d = exp(-1e-3 / 2.86e-3);

    hipMemsetAsync(d_ws, 0, 16, stream);   // zero repair counter

    wprep_kernel<<<(NWELEM + 255) / 256, 256, 0, stream>>>(W, whi, wlo);

    dim3 grid(2, 16, 64);  // cout-half x spatial tile x batch
    lif_conv_mfma_kernel<<<grid, 256, 0, stream>>>(P, Q, R, whi, wlo, bias, out,
                                                   pooled, cnt, list, cap,
                                                   use_pooled,
                                                   (float)alpha_d, (float)oma_d,
                                                   (float)gamma_d);

    repair_list_kernel<<<2048, 256, 0, stream>>>(P, Q, R, W, bias, out,
                                                 cnt, list, cap,
                                                 alpha_d, oma_d, gamma_d);

    float* ro = out + (size_t)2 * NPIX;
    ro_init<<<3, 256, 0, stream>>>(ro);

    if (use_pooled) {
        pool_fix_kernel<<<64, 256, 0, stream>>>(out, pooled, cnt, list, cap);
        readout_pooled_kernel<<<dim3(128, 8), 256, 0, stream>>>(pooled, wsig, ro);
    } else {
        readout_kernel<<<8192, 256, 0, stream>>>(out, wsig, ro);
    }
}